// Round 9
// baseline (277.723 us; speedup 1.0000x reference)
//
#include <hip/hip_runtime.h>

// SelfInteraction on MI355X.
// R8 = R7 resubmitted (previous bench died on infra: UnresponsiveContainer).
// M=128 x N=32 block tile (grid 64 zt x 4 hq) -> per-XCD B working set 3MB
// (L2-resident), 1-u-step chunks (8KB) via global_load_lds dbuf, full K per block
// (no cross-block reduction). PSTR=130 conflict-free x planes (128 rows).

#define C 128
#define NBATCH 8192

typedef _Float16 f16;
typedef _Float16 f16x8 __attribute__((ext_vector_type(8)));
typedef float f32x16 __attribute__((ext_vector_type(16)));
typedef unsigned int u32;

// ws layout:
// [0, 12MB)  : 3 f16 weight streams (ss, vv*inv_sqrt3, comb=Wsv+Wvs^T), each 2,097,152 f16
//              order [hq4][u128][vb4][kt2][lane64][j8]
//                <-> W[u][vb*32+kt*16+(l>>5)*8+j][hq*32+(l&31)]
// [12MB,32MB): raw channel sums f32 [5][8192][128]  (ss, vv_scaled, cb0, cb1, cb2)
#define WSTREAM_F16_PER_C 2097152             // 4 MB per stream
#define HQSL 524288                           // f16 per hq quarter (1 MB)
#define USL 4096                              // f16 per u-step slice (8 KB)
#define NSTREAM 3
#define RAW_OFF_BYTES ((size_t)NSTREAM*WSTREAM_F16_PER_C*2)  // 12 MB
#define PSTR 130               // 65 dwords/row: odd -> 1-bank shift per z-row
#define PLSZ (128*PSTR + 8)    // x-plane stride (f16), 4-dword inter-plane skew

__device__ __forceinline__ f16x8 splat8(f16 v) { return (f16x8){v, v, v, v, v, v, v, v}; }
__device__ __forceinline__ f32x16 mfma32(f16x8 a, f16x8 b, f32x16 c) {
    return __builtin_amdgcn_mfma_f32_32x32x16_f16(a, b, c, 0, 0, 0);
}
__device__ __forceinline__ void gl_lds16(const f16* g, f16* l) {
    __builtin_amdgcn_global_load_lds(
        (const __attribute__((address_space(1))) u32*)g,
        (__attribute__((address_space(3))) u32*)l, 16, 0, 0);
}

// ---------------- weight prep ----------------
// grid 384: c = blockIdx>>7 (0=ss, 1=vv*inv_sqrt3, 2=Wsv+Wvs^T), u = blockIdx&127
__global__ __launch_bounds__(256) void prep_weights(
        const float* __restrict__ Wss, const float* __restrict__ Wvv,
        const float* __restrict__ Wsv, const float* __restrict__ Wvs,
        f16* __restrict__ out) {
    __shared__ float lds[128 * 130];
    int c = blockIdx.x >> 7;
    int u = blockIdx.x & 127;
    if (c == 2) {
        for (int i = threadIdx.x; i < 16384; i += 256) {
            int v = i >> 7, w = i & 127;
            lds[v * 130 + w] = Wsv[(size_t)u * 16384 + i] + Wvs[(size_t)v * 16384 + u * 128 + w];
        }
    } else {
        const float* src = (c == 0 ? Wss : Wvv) + (size_t)u * 16384;
        float sc = (c == 0) ? 1.0f : 0.57735026918962576f;
        for (int i = threadIdx.x; i < 16384; i += 256) {
            int v = i >> 7, w = i & 127;
            lds[v * 130 + w] = sc * src[i];
        }
    }
    __syncthreads();
    f16* dst = out + (size_t)c * WSTREAM_F16_PER_C;
    for (int pos = threadIdx.x; pos < 2048; pos += 256) {
        int hq = pos >> 9, vb = (pos >> 7) & 3, kt = (pos >> 6) & 1, l = pos & 63;
        int v0 = vb * 32 + kt * 16 + ((l >> 5) << 3);
        int w = hq * 32 + (l & 31);
        f16x8 vals;
#pragma unroll
        for (int j = 0; j < 8; ++j) vals[j] = (f16)lds[(v0 + j) * 130 + w];
        size_t off = (size_t)hq * HQSL + (size_t)u * USL + (size_t)(vb * 2 + kt) * 512
                   + (size_t)l * 8;
        *(f16x8*)(dst + off) = vals;
    }
}

// 32x32 C/D tile write: row=(reg&3)+8*(reg>>2)+4*lk, col=l31
__device__ __forceinline__ void writeT32(float* __restrict__ raw, int c, int zrow0,
        int col0, int l31, int lk, const f32x16& a, bool st) {
#pragma unroll
    for (int reg = 0; reg < 16; ++reg) {
        int row = (reg & 3) + 8 * (reg >> 2) + 4 * lk;
        float* p = &raw[((size_t)c * NBATCH + zrow0 + row) * 128 + col0 + l31];
        if (st) *p = a[reg]; else *p += a[reg];
    }
}

// ---------------- main fused GEMM kernel ----------------
// grid 256: zb = bid>>2 (128-row z-tile), hq = bid&3 (32-col N-quarter; XCD-constant
// under %8 round-robin). 1024 thr = 16 waves. Chunk = 1 u-step (8KB) dbuf'd.
// ss/vv: wave=(mg2,vb4,kt2): M=64 (2 tiles), 1 B-frag -> 2 MFMA; 8 reduce rounds.
// cb:    wave=(mg4,vb4): M=32, kt in-wave, 3k fused: 2 B-frags -> 6 MFMA; 4 rounds.
__global__ __launch_bounds__(1024, 4) void si_main(
        const float* __restrict__ x, const f16* __restrict__ wstream,
        float* __restrict__ raw) {
    __shared__ f16 xp[4 * PLSZ];    // x planes [plane][z][v], 130 KB
    __shared__ f16 bst[2 * USL];    // B dbuf, 16 KB

    int zb = blockIdx.x >> 2;
    int hq = blockIdx.x & 3;
    int tid = threadIdx.x;

    const f16* sA = wstream + (size_t)hq * HQSL;
    const f16* sB = wstream + WSTREAM_F16_PER_C + (size_t)hq * HQSL;
    const f16* sC = wstream + (size_t)2 * WSTREAM_F16_PER_C + (size_t)hq * HQSL;

    // prologue: stage ss u=0 into buf0 (overlaps x staging)
    if (tid < 512) gl_lds16(sA + tid * 8, &bst[tid * 8]);

    // stage x tile (128 rows x 512 cols) into LDS planes
    for (int i = tid; i < 128 * 512; i += 1024) {
        int z = i >> 9, col = i & 511;
        f16 fv = (f16)x[(size_t)(zb * 128 + z) * 512 + col];
        if (col < 128) {
            xp[z * PSTR + col] = fv;
        } else {
            int cc = col - 128;
            int v = cc / 3, k = cc - v * 3;
            xp[(1 + k) * PLSZ + z * PSTR + v] = fv;
        }
    }
    __syncthreads();

    int lane = tid & 63, w = tid >> 6;
    int l31 = lane & 31, lk = lane >> 5;
    const bool stager = (tid < 512);

    // ================= phase 1: ss =================
    int mg = w >> 3, vb = (w >> 1) & 3, kt = w & 1;
    const int rm0 = (mg * 64 + l31) * PSTR, rm1 = rm0 + 32 * PSTR;
    const int segF = (vb * 2 + kt) * 512 + lane * 8;
    f32x16 accA = {}, accB = {};
    {
        f16x8 va0 = *(const f16x8*)&xp[rm0 + vb * 32 + kt * 16 + lk * 8];
        f16x8 va1 = *(const f16x8*)&xp[rm1 + vb * 32 + kt * 16 + lk * 8];
        for (int u = 0; u < 128; ++u) {
            int cur = (u & 1) * USL;
            if (u < 127 && stager)
                gl_lds16(sA + (size_t)(u + 1) * USL + tid * 8,
                         &bst[((u + 1) & 1) * USL + tid * 8]);
            f16x8 bf = *(const f16x8*)&bst[cur + segF];
            accA = mfma32(splat8(xp[rm0 + u]) * va0, bf, accA);
            accB = mfma32(splat8(xp[rm1 + u]) * va1, bf, accB);
            __syncthreads();
        }
    }
    // prefetch vv u=0 into buf0 (ss ended on buf1); drained by reduce barriers
    if (stager) gl_lds16(sB + tid * 8, &bst[tid * 8]);
    // ss reduce: 8 rounds keyed by (vb*2+kt)
#pragma unroll
    for (int r = 0; r < 8; ++r) {
        __threadfence_block();
        __syncthreads();
        if ((vb * 2 + kt) == r) {
            writeT32(raw, 0, zb * 128 + mg * 64,      hq * 32, l31, lk, accA, r == 0);
            writeT32(raw, 0, zb * 128 + mg * 64 + 32, hq * 32, l31, lk, accB, r == 0);
        }
    }
    __syncthreads();

    // ================= phase 2: vv =================
    f32x16 accVA = {}, accVB = {};
    {
        f16x8 wa0[3], wa1[3];
#pragma unroll
        for (int p = 0; p < 3; ++p) {
            wa0[p] = *(const f16x8*)&xp[(1 + p) * PLSZ + rm0 + vb * 32 + kt * 16 + lk * 8];
            wa1[p] = *(const f16x8*)&xp[(1 + p) * PLSZ + rm1 + vb * 32 + kt * 16 + lk * 8];
        }
        for (int u = 0; u < 128; ++u) {
            int cur = (u & 1) * USL;
            if (u < 127 && stager)
                gl_lds16(sB + (size_t)(u + 1) * USL + tid * 8,
                         &bst[((u + 1) & 1) * USL + tid * 8]);
            f16x8 bf = *(const f16x8*)&bst[cur + segF];
            f16x8 A0 = splat8(xp[1 * PLSZ + rm0 + u]) * wa0[0]
                     + splat8(xp[2 * PLSZ + rm0 + u]) * wa0[1]
                     + splat8(xp[3 * PLSZ + rm0 + u]) * wa0[2];
            f16x8 A1 = splat8(xp[1 * PLSZ + rm1 + u]) * wa1[0]
                     + splat8(xp[2 * PLSZ + rm1 + u]) * wa1[1]
                     + splat8(xp[3 * PLSZ + rm1 + u]) * wa1[2];
            accVA = mfma32(A0, bf, accVA);
            accVB = mfma32(A1, bf, accVB);
            __syncthreads();
        }
    }
    // prefetch cb u=0 into buf0
    if (stager) gl_lds16(sC + tid * 8, &bst[tid * 8]);
    // vv reduce: 8 rounds
#pragma unroll
    for (int r = 0; r < 8; ++r) {
        __threadfence_block();
        __syncthreads();
        if ((vb * 2 + kt) == r) {
            writeT32(raw, 1, zb * 128 + mg * 64,      hq * 32, l31, lk, accVA, r == 0);
            writeT32(raw, 1, zb * 128 + mg * 64 + 32, hq * 32, l31, lk, accVB, r == 0);
        }
    }
    __syncthreads();

    // ================= phase 3: cb (3k fused, kt in-wave) =================
    int mgc = w >> 2, vbc = w & 3;
    const int rowm = (mgc * 32 + l31) * PSTR;
    const int seg0 = (vbc * 2) * 512 + lane * 8;
    f32x16 acc2[3] = {};
    {
        f16x8 vvb[3][2];
#pragma unroll
        for (int p = 0; p < 3; ++p)
#pragma unroll
            for (int tt = 0; tt < 2; ++tt)
                vvb[p][tt] = *(const f16x8*)&xp[(1 + p) * PLSZ + rowm
                                                + vbc * 32 + tt * 16 + lk * 8];
        for (int u = 0; u < 128; ++u) {
            int cur = (u & 1) * USL;
            if (u < 127 && stager)
                gl_lds16(sC + (size_t)(u + 1) * USL + tid * 8,
                         &bst[((u + 1) & 1) * USL + tid * 8]);
            f16x8 b0 = *(const f16x8*)&bst[cur + seg0];
            f16x8 b1 = *(const f16x8*)&bst[cur + seg0 + 512];
            f16x8 sp = splat8(xp[rowm + u]);
#pragma unroll
            for (int k = 0; k < 3; ++k) {
                acc2[k] = mfma32(sp * vvb[k][0], b0, acc2[k]);
                acc2[k] = mfma32(sp * vvb[k][1], b1, acc2[k]);
            }
            __syncthreads();
        }
    }
    // cb reduce: 4 rotated rounds keyed by vbc
#pragma unroll
    for (int r = 0; r < 4; ++r) {
        __threadfence_block();
        __syncthreads();
        int k = (vbc - r) & 3;
        if (k == 0)      writeT32(raw, 2, zb * 128 + mgc * 32, hq * 32, l31, lk, acc2[0], r == 0);
        else if (k == 1) writeT32(raw, 3, zb * 128 + mgc * 32, hq * 32, l31, lk, acc2[1], r == 0);
        else if (k == 2) writeT32(raw, 4, zb * 128 + mgc * 32, hq * 32, l31, lk, acc2[2], r == 0);
    }
}

// ---------------- finalize ----------------
__global__ __launch_bounds__(64) void si_finalize(const float* __restrict__ raw,
                                                  float* __restrict__ out) {
    const float PW0 = 0.0055242717280199f;   // 1/sqrt(2*128*128) == pw1/sqrt(3)
    int z = blockIdx.x;
    int t = threadIdx.x;
    const size_t CS = (size_t)NBATCH * 128;
    const float* r0 = raw + (size_t)z * 128;

    float y0A = PW0 * (r0[t] + r0[CS + t]);
    float y0B = PW0 * (r0[t + 64] + r0[CS + t + 64]);
    float s1 = y0A + y0B, s2 = y0A * y0A + y0B * y0B;
    for (int o = 32; o; o >>= 1) {
        s1 += __shfl_xor(s1, o);
        s2 += __shfl_xor(s2, o);
    }
    float mean = s1 * (1.0f / 128.0f);
    float var = (s2 - 128.0f * mean * mean) * (1.0f / 127.0f);
    float sc = 1.0f / (sqrtf(fmaxf(var, 0.0f)) + 1e-9f);
    out[(size_t)z * 512 + t] = y0A * sc;
    out[(size_t)z * 512 + t + 64] = y0B * sc;

    float yA[3], yB[3];
    float nA = 1e-9f, nB = 1e-9f;
#pragma unroll
    for (int k = 0; k < 3; ++k) {
        yA[k] = PW0 * r0[CS * (2 + k) + t];
        yB[k] = PW0 * r0[CS * (2 + k) + t + 64];
        nA += yA[k] * yA[k];
        nB += yB[k] * yB[k];
    }
    nA = sqrtf(nA);
    nB = sqrtf(nB);
    float t1 = nA + nB, t2 = nA * nA + nB * nB;
    for (int o = 32; o; o >>= 1) {
        t1 += __shfl_xor(t1, o);
        t2 += __shfl_xor(t2, o);
    }
    float meanv = t1 * (1.0f / 128.0f);
    float varv = (t2 - 128.0f * meanv * meanv) * (1.0f / 127.0f);
    float sv = 1.0f / (sqrtf(fmaxf(varv, 0.0f)) + 1e-9f);
#pragma unroll
    for (int k = 0; k < 3; ++k) {
        out[(size_t)z * 512 + 128 + t * 3 + k] = yA[k] * sv;
        out[(size_t)z * 512 + 128 + (t + 64) * 3 + k] = yB[k] * sv;
    }
}

extern "C" void kernel_launch(void* const* d_in, const int* in_sizes, int n_in,
                              void* d_out, int out_size, void* d_ws, size_t ws_size,
                              hipStream_t stream) {
    const float* x = (const float*)d_in[0];
    const float* Wss = (const float*)d_in[1];
    const float* Wvv = (const float*)d_in[2];
    const float* Wsv = (const float*)d_in[3];
    const float* Wvs = (const float*)d_in[4];
    f16* wstream = (f16*)d_ws;
    float* raw = (float*)((char*)d_ws + RAW_OFF_BYTES);
    float* out = (float*)d_out;

    hipLaunchKernelGGL(prep_weights, dim3(384), dim3(256), 0, stream,
                       Wss, Wvv, Wsv, Wvs, wstream);
    hipLaunchKernelGGL(si_main, dim3(256), dim3(1024), 0, stream, x, wstream, raw);
    hipLaunchKernelGGL(si_finalize, dim3(NBATCH), dim3(64), 0, stream, raw, out);
}

// Round 11
// 263.449 us; speedup vs baseline: 1.0542x; 1.0542x over previous
//
#include <hip/hip_runtime.h>

// SelfInteraction on MI355X.
// R10 = R9 resubmitted (bench died on infra: UnresponsiveContainer, kernel never ran).
// B per-lane from global (NO K-loop barriers), 4-deep named-register prefetch
// (unroll-8, static sets, linear addresses), PSTR=136 aligned LDS planes, splat
// scalars batched via b128 (1 per 8 u-steps). M=128 x N=32 tile, full K per block,
// hq XCD-affine (per-XCD B set 3MB L2-resident).

#define C 128
#define NBATCH 8192

typedef _Float16 f16;
typedef _Float16 f16x8 __attribute__((ext_vector_type(8)));
typedef float f32x16 __attribute__((ext_vector_type(16)));
typedef unsigned int u32;

// ws layout:
// [0, 12MB)  : 3 f16 weight streams (ss, vv*inv_sqrt3, comb=Wsv+Wvs^T), each 2,097,152 f16
//              order [hq4][u128][vb4][kt2][lane64][j8]
//                <-> W[u][vb*32+kt*16+(l>>5)*8+j][hq*32+(l&31)]
// [12MB,32MB): raw channel sums f32 [5][8192][128]  (ss, vv_scaled, cb0, cb1, cb2)
#define WSTREAM_F16_PER_C 2097152             // 4 MB per stream
#define HQSL 524288                           // f16 per hq quarter (1 MB)
#define USL 4096                              // f16 per u-step slice (8 KB)
#define NSTREAM 3
#define RAW_OFF_BYTES ((size_t)NSTREAM*WSTREAM_F16_PER_C*2)  // 12 MB
#define PSTR 136               // f16/row: 272B = 17x16B -> b128-aligned rows
#define PLSZ (128*PSTR + 8)    // x-plane stride (f16), 16B inter-plane skew

__device__ __forceinline__ f16x8 splat8(f16 v) { return (f16x8){v, v, v, v, v, v, v, v}; }
union U16x8 { uint4 u; f16x8 h; };
__device__ __forceinline__ f16x8 as_h8(uint4 v) { U16x8 x; x.u = v; return x.h; }
__device__ __forceinline__ f32x16 mfma32(f16x8 a, f16x8 b, f32x16 c) {
    return __builtin_amdgcn_mfma_f32_32x32x16_f16(a, b, c, 0, 0, 0);
}

// ---------------- weight prep (identical layout to R8) ----------------
__global__ __launch_bounds__(256) void prep_weights(
        const float* __restrict__ Wss, const float* __restrict__ Wvv,
        const float* __restrict__ Wsv, const float* __restrict__ Wvs,
        f16* __restrict__ out) {
    __shared__ float lds[128 * 130];
    int c = blockIdx.x >> 7;
    int u = blockIdx.x & 127;
    if (c == 2) {
        for (int i = threadIdx.x; i < 16384; i += 256) {
            int v = i >> 7, w = i & 127;
            lds[v * 130 + w] = Wsv[(size_t)u * 16384 + i] + Wvs[(size_t)v * 16384 + u * 128 + w];
        }
    } else {
        const float* src = (c == 0 ? Wss : Wvv) + (size_t)u * 16384;
        float sc = (c == 0) ? 1.0f : 0.57735026918962576f;
        for (int i = threadIdx.x; i < 16384; i += 256) {
            int v = i >> 7, w = i & 127;
            lds[v * 130 + w] = sc * src[i];
        }
    }
    __syncthreads();
    f16* dst = out + (size_t)c * WSTREAM_F16_PER_C;
    for (int pos = threadIdx.x; pos < 2048; pos += 256) {
        int hq = pos >> 9, vb = (pos >> 7) & 3, kt = (pos >> 6) & 1, l = pos & 63;
        int v0 = vb * 32 + kt * 16 + ((l >> 5) << 3);
        int w = hq * 32 + (l & 31);
        f16x8 vals;
#pragma unroll
        for (int j = 0; j < 8; ++j) vals[j] = (f16)lds[(v0 + j) * 130 + w];
        size_t off = (size_t)hq * HQSL + (size_t)u * USL + (size_t)(vb * 2 + kt) * 512
                   + (size_t)l * 8;
        *(f16x8*)(dst + off) = vals;
    }
}

// 32x32 C/D tile write: row=(reg&3)+8*(reg>>2)+4*lk, col=l31
__device__ __forceinline__ void writeT32(float* __restrict__ raw, int c, int zrow0,
        int col0, int l31, int lk, const f32x16& a, bool st) {
#pragma unroll
    for (int reg = 0; reg < 16; ++reg) {
        int row = (reg & 3) + 8 * (reg >> 2) + 4 * lk;
        float* p = &raw[((size_t)c * NBATCH + zrow0 + row) * 128 + col0 + l31];
        if (st) *p = a[reg]; else *p += a[reg];
    }
}

// ---------------- main fused GEMM kernel ----------------
// grid 256: zb = bid>>2 (128-row z-tile), hq = bid&3 (32-col N-quarter, XCD-affine).
// 1024 thr = 16 waves. B read per-lane from global (uint4), depth-4 named prefetch.
// ss/vv: wave=(mg2,vb4,kt2), M=64: 1 frag -> 2 MFMA/u. cb: wave=(mg4,vb4), kt in-wave,
// 3k fused: 2 frags -> 6 MFMA/u, depth-2.
__global__ __launch_bounds__(1024, 4) void si_main(
        const float* __restrict__ x, const f16* __restrict__ wstream,
        float* __restrict__ raw) {
    __shared__ f16 xp[4 * PLSZ];    // x planes [plane][z][v], 139 KB

    int zb = blockIdx.x >> 2;
    int hq = blockIdx.x & 3;
    int tid = threadIdx.x;

    const f16* sA = wstream + (size_t)hq * HQSL;
    const f16* sB = wstream + WSTREAM_F16_PER_C + (size_t)hq * HQSL;
    const f16* sC = wstream + (size_t)2 * WSTREAM_F16_PER_C + (size_t)hq * HQSL;

    // stage x tile (128 rows x 512 cols) into LDS planes
    for (int i = tid; i < 128 * 512; i += 1024) {
        int z = i >> 9, col = i & 511;
        f16 fv = (f16)x[(size_t)(zb * 128 + z) * 512 + col];
        if (col < 128) {
            xp[z * PSTR + col] = fv;
        } else {
            int cc = col - 128;
            int v = cc / 3, k = cc - v * 3;
            xp[(1 + k) * PLSZ + z * PSTR + v] = fv;
        }
    }
    __syncthreads();

    int lane = tid & 63, w = tid >> 6;
    int l31 = lane & 31, lk = lane >> 5;

    // ================= phase 1: ss =================
    int mg = w >> 3, vb = (w >> 1) & 3, kt = w & 1;
    const int rm0 = (mg * 64 + l31) * PSTR, rm1 = rm0 + 32 * PSTR;
    f32x16 accA = {}, accB = {};
    {
        const uint4* bl = (const uint4*)sA + (vb * 2 + kt) * 64 + lane;
        f16x8 va0 = *(const f16x8*)&xp[rm0 + vb * 32 + kt * 16 + lk * 8];
        f16x8 va1 = *(const f16x8*)&xp[rm1 + vb * 32 + kt * 16 + lk * 8];
        uint4 B0 = bl[0], B1 = bl[512], B2 = bl[1024], B3 = bl[1536];
        for (int g = 0; g < 16; ++g) {
            f16x8 s0v = *(const f16x8*)&xp[rm0 + g * 8];
            f16x8 s1v = *(const f16x8*)&xp[rm1 + g * 8];
#define SS_STEP(j, Bq)                                                  \
            {                                                           \
                accA = mfma32(splat8(s0v[j]) * va0, as_h8(Bq), accA);   \
                accB = mfma32(splat8(s1v[j]) * va1, as_h8(Bq), accB);   \
                int u_ = g * 8 + j;                                     \
                int up_ = u_ + 4 < 128 ? u_ + 4 : 127;                  \
                Bq = bl[(size_t)up_ * 512];                             \
            }
            SS_STEP(0, B0) SS_STEP(1, B1) SS_STEP(2, B2) SS_STEP(3, B3)
            SS_STEP(4, B0) SS_STEP(5, B1) SS_STEP(6, B2) SS_STEP(7, B3)
#undef SS_STEP
        }
    }
#pragma unroll
    for (int r = 0; r < 8; ++r) {
        __threadfence_block();
        __syncthreads();
        if ((vb * 2 + kt) == r) {
            writeT32(raw, 0, zb * 128 + mg * 64,      hq * 32, l31, lk, accA, r == 0);
            writeT32(raw, 0, zb * 128 + mg * 64 + 32, hq * 32, l31, lk, accB, r == 0);
        }
    }

    // ================= phase 2: vv =================
    f32x16 accVA = {}, accVB = {};
    {
        const uint4* bl = (const uint4*)sB + (vb * 2 + kt) * 64 + lane;
        f16x8 wa0[3], wa1[3];
#pragma unroll
        for (int p = 0; p < 3; ++p) {
            wa0[p] = *(const f16x8*)&xp[(1 + p) * PLSZ + rm0 + vb * 32 + kt * 16 + lk * 8];
            wa1[p] = *(const f16x8*)&xp[(1 + p) * PLSZ + rm1 + vb * 32 + kt * 16 + lk * 8];
        }
        uint4 B0 = bl[0], B1 = bl[512], B2 = bl[1024], B3 = bl[1536];
        for (int g = 0; g < 16; ++g) {
            f16x8 p00 = *(const f16x8*)&xp[1 * PLSZ + rm0 + g * 8];
            f16x8 p01 = *(const f16x8*)&xp[2 * PLSZ + rm0 + g * 8];
            f16x8 p02 = *(const f16x8*)&xp[3 * PLSZ + rm0 + g * 8];
            f16x8 p10 = *(const f16x8*)&xp[1 * PLSZ + rm1 + g * 8];
            f16x8 p11 = *(const f16x8*)&xp[2 * PLSZ + rm1 + g * 8];
            f16x8 p12 = *(const f16x8*)&xp[3 * PLSZ + rm1 + g * 8];
#define VV_STEP(j, Bq)                                                  \
            {                                                           \
                f16x8 A0 = splat8(p00[j]) * wa0[0]                      \
                         + splat8(p01[j]) * wa0[1]                      \
                         + splat8(p02[j]) * wa0[2];                     \
                f16x8 A1 = splat8(p10[j]) * wa1[0]                      \
                         + splat8(p11[j]) * wa1[1]                      \
                         + splat8(p12[j]) * wa1[2];                     \
                accVA = mfma32(A0, as_h8(Bq), accVA);                   \
                accVB = mfma32(A1, as_h8(Bq), accVB);                   \
                int u_ = g * 8 + j;                                     \
                int up_ = u_ + 4 < 128 ? u_ + 4 : 127;                  \
                Bq = bl[(size_t)up_ * 512];                             \
            }
            VV_STEP(0, B0) VV_STEP(1, B1) VV_STEP(2, B2) VV_STEP(3, B3)
            VV_STEP(4, B0) VV_STEP(5, B1) VV_STEP(6, B2) VV_STEP(7, B3)
#undef VV_STEP
        }
    }
#pragma unroll
    for (int r = 0; r < 8; ++r) {
        __threadfence_block();
        __syncthreads();
        if ((vb * 2 + kt) == r) {
            writeT32(raw, 1, zb * 128 + mg * 64,      hq * 32, l31, lk, accVA, r == 0);
            writeT32(raw, 1, zb * 128 + mg * 64 + 32, hq * 32, l31, lk, accVB, r == 0);
        }
    }

    // ================= phase 3: cb (3k fused, kt in-wave, depth-2) =================
    int mgc = w >> 2, vbc = w & 3;
    const int rowm = (mgc * 32 + l31) * PSTR;
    f32x16 acc2[3] = {};
    {
        const uint4* bl = (const uint4*)sC + (vbc * 2) * 64 + lane;
        f16x8 vvb[3][2];
#pragma unroll
        for (int p = 0; p < 3; ++p)
#pragma unroll
            for (int tt = 0; tt < 2; ++tt)
                vvb[p][tt] = *(const f16x8*)&xp[(1 + p) * PLSZ + rowm
                                                + vbc * 32 + tt * 16 + lk * 8];
        uint4 C00 = bl[0],   C01 = bl[64];      // u=0: kt0, kt1
        uint4 C10 = bl[512], C11 = bl[576];     // u=1
        for (int g = 0; g < 16; ++g) {
            f16x8 spv = *(const f16x8*)&xp[rowm + g * 8];
#define CB_STEP(j, Ca, Cb)                                              \
            {                                                           \
                f16x8 sp = splat8(spv[j]);                              \
                acc2[0] = mfma32(sp * vvb[0][0], as_h8(Ca), acc2[0]);   \
                acc2[0] = mfma32(sp * vvb[0][1], as_h8(Cb), acc2[0]);   \
                acc2[1] = mfma32(sp * vvb[1][0], as_h8(Ca), acc2[1]);   \
                acc2[1] = mfma32(sp * vvb[1][1], as_h8(Cb), acc2[1]);   \
                acc2[2] = mfma32(sp * vvb[2][0], as_h8(Ca), acc2[2]);   \
                acc2[2] = mfma32(sp * vvb[2][1], as_h8(Cb), acc2[2]);   \
                int u_ = g * 8 + j;                                     \
                int up_ = u_ + 2 < 128 ? u_ + 2 : 127;                  \
                Ca = bl[(size_t)up_ * 512];                             \
                Cb = bl[(size_t)up_ * 512 + 64];                        \
            }
            CB_STEP(0, C00, C01) CB_STEP(1, C10, C11)
            CB_STEP(2, C00, C01) CB_STEP(3, C10, C11)
            CB_STEP(4, C00, C01) CB_STEP(5, C10, C11)
            CB_STEP(6, C00, C01) CB_STEP(7, C10, C11)
#undef CB_STEP
        }
    }
    // cb reduce: 4 rotated rounds keyed by vbc
#pragma unroll
    for (int r = 0; r < 4; ++r) {
        __threadfence_block();
        __syncthreads();
        int k = (vbc - r) & 3;
        if (k == 0)      writeT32(raw, 2, zb * 128 + mgc * 32, hq * 32, l31, lk, acc2[0], r == 0);
        else if (k == 1) writeT32(raw, 3, zb * 128 + mgc * 32, hq * 32, l31, lk, acc2[1], r == 0);
        else if (k == 2) writeT32(raw, 4, zb * 128 + mgc * 32, hq * 32, l31, lk, acc2[2], r == 0);
    }
}

// ---------------- finalize ----------------
__global__ __launch_bounds__(64) void si_finalize(const float* __restrict__ raw,
                                                  float* __restrict__ out) {
    const float PW0 = 0.0055242717280199f;   // 1/sqrt(2*128*128) == pw1/sqrt(3)
    int z = blockIdx.x;
    int t = threadIdx.x;
    const size_t CS = (size_t)NBATCH * 128;
    const float* r0 = raw + (size_t)z * 128;

    float y0A = PW0 * (r0[t] + r0[CS + t]);
    float y0B = PW0 * (r0[t + 64] + r0[CS + t + 64]);
    float s1 = y0A + y0B, s2 = y0A * y0A + y0B * y0B;
    for (int o = 32; o; o >>= 1) {
        s1 += __shfl_xor(s1, o);
        s2 += __shfl_xor(s2, o);
    }
    float mean = s1 * (1.0f / 128.0f);
    float var = (s2 - 128.0f * mean * mean) * (1.0f / 127.0f);
    float sc = 1.0f / (sqrtf(fmaxf(var, 0.0f)) + 1e-9f);
    out[(size_t)z * 512 + t] = y0A * sc;
    out[(size_t)z * 512 + t + 64] = y0B * sc;

    float yA[3], yB[3];
    float nA = 1e-9f, nB = 1e-9f;
#pragma unroll
    for (int k = 0; k < 3; ++k) {
        yA[k] = PW0 * r0[CS * (2 + k) + t];
        yB[k] = PW0 * r0[CS * (2 + k) + t + 64];
        nA += yA[k] * yA[k];
        nB += yB[k] * yB[k];
    }
    nA = sqrtf(nA);
    nB = sqrtf(nB);
    float t1 = nA + nB, t2 = nA * nA + nB * nB;
    for (int o = 32; o; o >>= 1) {
        t1 += __shfl_xor(t1, o);
        t2 += __shfl_xor(t2, o);
    }
    float meanv = t1 * (1.0f / 128.0f);
    float varv = (t2 - 128.0f * meanv * meanv) * (1.0f / 127.0f);
    float sv = 1.0f / (sqrtf(fmaxf(varv, 0.0f)) + 1e-9f);
#pragma unroll
    for (int k = 0; k < 3; ++k) {
        out[(size_t)z * 512 + 128 + t * 3 + k] = yA[k] * sv;
        out[(size_t)z * 512 + 128 + (t + 64) * 3 + k] = yB[k] * sv;
    }
}

extern "C" void kernel_launch(void* const* d_in, const int* in_sizes, int n_in,
                              void* d_out, int out_size, void* d_ws, size_t ws_size,
                              hipStream_t stream) {
    const float* x = (const float*)d_in[0];
    const float* Wss = (const float*)d_in[1];
    const float* Wvv = (const float*)d_in[2];
    const float* Wsv = (const float*)d_in[3];
    const float* Wvs = (const float*)d_in[4];
    f16* wstream = (f16*)d_ws;
    float* raw = (float*)((char*)d_ws + RAW_OFF_BYTES);
    float* out = (float*)d_out;

    hipLaunchKernelGGL(prep_weights, dim3(384), dim3(256), 0, stream,
                       Wss, Wvv, Wsv, Wvs, wstream);
    hipLaunchKernelGGL(si_main, dim3(256), dim3(1024), 0, stream, x, wstream, raw);
    hipLaunchKernelGGL(si_finalize, dim3(NBATCH), dim3(64), 0, stream, raw, out);
}